// Round 1
// baseline (395.425 us; speedup 1.0000x reference)
//
#include <hip/hip_runtime.h>

typedef float f32x4 __attribute__((ext_vector_type(4)));
typedef short s16x8 __attribute__((ext_vector_type(8)));

constexpr int NL  = 31;     // num labels
constexpr int BB  = 64;     // batch
constexpr int TT  = 512;    // time
constexpr int DD  = 768;    // feature dim
constexpr int RTOT = BB * TT;         // 32768 rows
constexpr int IDX_EOS = 29;
constexpr int IDX_BOS = 30;
constexpr float LOG2E = 1.4426950408889634f;
constexpr float LN2F  = 0.6931471805599453f;

union FragU { unsigned u[4]; s16x8 s; };

__device__ inline unsigned pk_bf16(float a, float b) {
  unsigned ua = __float_as_uint(a), ub = __float_as_uint(b);
  ua = (ua + 0x7fffu + ((ua >> 16) & 1u)) >> 16;   // RNE f32->bf16
  ub = (ub + 0x7fffu + ((ub >> 16) & 1u)) >> 16;
  return ua | (ub << 16);
}

__device__ inline s16x8 load_frag(const float* p) {
  f32x4 a = *(const f32x4*)p;
  f32x4 c = *(const f32x4*)(p + 4);
  FragU f;
  f.u[0] = pk_bf16(a[0], a[1]);
  f.u[1] = pk_bf16(a[2], a[3]);
  f.u[2] = pk_bf16(c[0], c[1]);
  f.u[3] = pk_bf16(c[2], c[3]);
  return f.s;
}

// ---------------- K1: out_s[r][l] = input[r,:] . state_w[l,:] + state_b[l] ---
// MFMA bf16 16x16x32. Each wave: 2 row-tiles of 16 (32 rows), N padded 31->32
// (two 16-col halves). Block = 4 waves = 128 rows; grid = 256 blocks.
__global__ __launch_bounds__(256) void k_outs(
    const float* __restrict__ inp, const float* __restrict__ sw,
    const float* __restrict__ sb, const float* __restrict__ msk,
    float* __restrict__ outs)
{
  int tid  = threadIdx.x;
  int wave = tid >> 6, lane = tid & 63;
  int quad = lane >> 4, l15 = lane & 15;
  int rowbase = blockIdx.x * 128 + wave * 32;

  f32x4 acc[2][2] = {};
  for (int s = 0; s < DD / 32; ++s) {
    int kb = s * 32 + quad * 8;
    s16x8 bf[2];
#pragma unroll
    for (int h = 0; h < 2; ++h) {
      int n = h * 16 + l15;
      if (n < NL) {
        bf[h] = load_frag(sw + n * DD + kb);     // B^T layout: [n][k]
      } else {
        FragU z; z.u[0] = z.u[1] = z.u[2] = z.u[3] = 0; bf[h] = z.s;
      }
    }
#pragma unroll
    for (int t = 0; t < 2; ++t) {
      int row = rowbase + t * 16 + l15;
      s16x8 af = load_frag(inp + (size_t)row * DD + kb);  // A layout: [m][k]
      acc[t][0] = __builtin_amdgcn_mfma_f32_16x16x32_bf16(af, bf[0], acc[t][0], 0, 0, 0);
      acc[t][1] = __builtin_amdgcn_mfma_f32_16x16x32_bf16(af, bf[1], acc[t][1], 0, 0, 0);
    }
  }
  // C/D layout: col n = lane&15 (per h), row m = quad*4 + reg   [m89-verified]
#pragma unroll
  for (int t = 0; t < 2; ++t) {
#pragma unroll
    for (int h = 0; h < 2; ++h) {
      int n = h * 16 + l15;
      if (n >= NL) continue;
      float bias = sb[n];
#pragma unroll
      for (int r = 0; r < 4; ++r) {
        int row = rowbase + t * 16 + quad * 4 + r;
        float v = acc[t][h][r] + bias;
        if (n == IDX_EOS && msk[row] == 0.f) v += 20000.f;
        outs[(size_t)row * NL + n] = v;
      }
    }
  }
}

// ------------- wave-level helpers (32-lane groups) ---------------------------
__device__ inline float bfly_max32(float v) {
#define STEPM(K) { float o = __int_as_float(__builtin_amdgcn_ds_swizzle(__float_as_int(v), ((K) << 10) | 0x1f)); v = fmaxf(v, o); }
  STEPM(1) STEPM(2) STEPM(4) STEPM(8) STEPM(16)
#undef STEPM
  return v;
}
__device__ inline float bfly_sum32(float v) {
#define STEPS(K) { float o = __int_as_float(__builtin_amdgcn_ds_swizzle(__float_as_int(v), ((K) << 10) | 0x1f)); v = v + o; }
  STEPS(1) STEPS(2) STEPS(4) STEPS(8) STEPS(16)
#undef STEPS
  return v;
}

// ---------------- K2: scan blocks (0..15) + energy blocks (16..1039) --------
// Scan (prob space): P'[j] = (sum_i W[i,j] P[i]) * U[t,j],
//   W = exp(trans) (exact 0 at -1e4 entries), U = exp(out_s[t,j]).
// One batch per wave. i-dim split: lanes 0-31 handle i in [0,16), lanes 32-63
// i in [16,31). p-storage: each 32-group's local lanes 0..15 hold its i-half's
// P values (so the 16 ds_swizzle broadcast imms are wave-uniform).
__global__ __launch_bounds__(256) void k_main(
    const float* __restrict__ outs, const float* __restrict__ trans,
    const int* __restrict__ target, float* __restrict__ energy,
    float* __restrict__ ws_tgt, float* __restrict__ ws_lse)
{
  __shared__ float tr[961];
  __shared__ float oshm[32 * NL];

  int bid = blockIdx.x;
  if (bid < 16) {
    int tid = threadIdx.x;
    int wave = tid >> 6, lane = tid & 63;
    int b = bid * 4 + wave;
    int q = lane & 31;                 // column j (31 => dead lane)
    int qc = (q < NL) ? q : 0;         // clamped for loads
    int i0 = (lane >> 5) * 16;         // this half's i-base

    // weights W[i][q] for my i-half; zero for i>=31 or q==31
    float wv[16];
#pragma unroll
    for (int ii = 0; ii < 16; ++ii) {
      int i = i0 + ii;
      int ic = (i < NL) ? i : 0;
      float w = exp2f(LOG2E * trans[ic * NL + qc]);
      wv[ii] = (i < NL && q < NL) ? w : 0.f;
    }
    float We = (q < NL) ? exp2f(LOG2E * trans[qc * NL + IDX_EOS]) : 0.f;

    // redistribute index: lane<32 keeps p'[lane]; lanes 32..47 fetch p'[q+16]
    int bidx = (((lane >= 32) && (q < 16)) ? (q + 16) : lane) << 2;
    const float* osb = outs + (size_t)b * TT * NL;

    float p0 = (q < NL) ? exp2f(LOG2E * (trans[IDX_BOS * NL + qc] + osb[qc])) : 0.f;
    float p = __int_as_float(__builtin_amdgcn_ds_bpermute(bidx, __float_as_int(p0)));
    float M2 = 0.f;

    float ucur = osb[1 * NL + qc];
    for (int t = 1; t < TT; ++t) {
      int tn = (t < TT - 1) ? t + 1 : t;
      float unext = osb[tn * NL + qc];

      int pbits = __float_as_int(p);
      float s0 = 0.f, s1 = 0.f, s2 = 0.f, s3 = 0.f;
#define BCAST(II, ACC) { float pv = __int_as_float(__builtin_amdgcn_ds_swizzle(pbits, (II) << 5)); ACC = fmaf(wv[II], pv, ACC); }
      BCAST(0, s0)  BCAST(1, s1)  BCAST(2, s2)  BCAST(3, s3)
      BCAST(4, s0)  BCAST(5, s1)  BCAST(6, s2)  BCAST(7, s3)
      BCAST(8, s0)  BCAST(9, s1)  BCAST(10, s2) BCAST(11, s3)
      BCAST(12, s0) BCAST(13, s1) BCAST(14, s2) BCAST(15, s3)
#undef BCAST
      float s = (s0 + s1) + (s2 + s3);
      // combine the two i-halves
      float sp = __int_as_float(__builtin_amdgcn_ds_bpermute((lane ^ 32) << 2, __float_as_int(s)));
      float pn = (s + sp) * exp2f(LOG2E * ucur);

      if ((t & 7) == 0) {              // renorm (before redistribute: both
        float m = bfly_max32(pn);      //  groups see identical pn sets)
        float lg = log2f(m);
        M2 += lg;
        pn *= exp2f(-lg);
      }
      p = __int_as_float(__builtin_amdgcn_ds_bpermute(bidx, __float_as_int(pn)));
      ucur = unext;
    }
    // loss lse: ln2*(M2 + log2(sum_j p[j]*exp(trans[j,EOS])))
    // g0 storage holds p'[0..31] directly; lane 0 is in g0.
    float vsum = bfly_sum32((q < NL) ? p * We : 0.f);
    if (lane == 0) ws_lse[b] = LN2F * (M2 + log2f(vsum));
    return;
  }

  // ---- energy blocks: 32 rows each ----
  int eb = bid - 16;
  int r0 = eb * 32;
  for (int idx = threadIdx.x; idx < 961; idx += 256) tr[idx] = trans[idx];
  for (int idx = threadIdx.x; idx < 32 * NL; idx += 256)
    oshm[idx] = outs[(size_t)r0 * NL + idx];
  __syncthreads();

  // tgt_energy partials: one lane per row, reduce 32 lanes, one atomic
  if (threadIdx.x < 32) {
    int r = r0 + threadIdx.x;
    int tgt = target[r];
    int prv = ((r & (TT - 1)) == 0) ? IDX_BOS : target[r - 1];
    float c = tr[prv * NL + tgt] + oshm[threadIdx.x * NL + tgt];
    for (int off = 16; off; off >>= 1) c += __shfl_down(c, off, 32);
    if (threadIdx.x == 0) atomicAdd(&ws_tgt[r0 / TT], c);
  }

  // energy[r][e] = trans[e] + out_s[r][e % 31], e in [0,961)
  int e0 = threadIdx.x, e1 = e0 + 256, e2 = e0 + 512, e3 = e0 + 768;
  float t0 = tr[e0], t1 = tr[e1], t2 = tr[e2];
  bool w3 = (e3 < 961);
  float t3 = w3 ? tr[e3] : 0.f;
  int j0 = e0 % 31, j1 = e1 % 31, j2 = e2 % 31, j3 = e3 % 31;
  for (int rr = 0; rr < 32; ++rr) {
    const float* ob = &oshm[rr * NL];
    float* dst = energy + (size_t)(r0 + rr) * 961;
    dst[e0] = t0 + ob[j0];
    dst[e1] = t1 + ob[j1];
    dst[e2] = t2 + ob[j2];
    if (w3) dst[e3] = t3 + ob[j3];
  }
}

// ---------------- K3: loss[b] = lse[b] - tgt_energy[b] ----------------------
__global__ void k_loss(const float* __restrict__ ws_lse,
                       const float* __restrict__ ws_tgt,
                       float* __restrict__ loss)
{
  int b = threadIdx.x;
  if (b < BB) loss[b] = ws_lse[b] - ws_tgt[b];
}

extern "C" void kernel_launch(void* const* d_in, const int* in_sizes, int n_in,
                              void* d_out, int out_size, void* d_ws, size_t ws_size,
                              hipStream_t stream) {
  const float* inp   = (const float*)d_in[0];   // (64,512,768) f32
  const int*   tgt   = (const int*)d_in[1];     // (64,512) int
  const float* msk   = (const float*)d_in[2];   // (64,512) f32
  const float* sw    = (const float*)d_in[3];   // (31,768) f32
  const float* sb    = (const float*)d_in[4];   // (31,) f32
  const float* trans = (const float*)d_in[5];   // (31,31) f32

  float* out  = (float*)d_out;                  // [0,64): loss; [64,...): energy
  float* outs = (float*)d_ws;                   // out_s: 32768*31 f32 (~4.06 MB)
  float* ws_tgt = outs + (size_t)RTOT * NL;     // 64 f32 (atomic accum)
  float* ws_lse = ws_tgt + 64;                  // 64 f32

  hipMemsetAsync(ws_tgt, 0, 64 * sizeof(float), stream);
  k_outs<<<RTOT / 128, 256, 0, stream>>>(inp, sw, sb, msk, outs);
  k_main<<<16 + RTOT / 32, 256, 0, stream>>>(outs, trans, tgt, out + BB, ws_tgt, ws_lse);
  k_loss<<<1, 64, 0, stream>>>(ws_lse, ws_tgt, out);
}

// Round 2
// 393.178 us; speedup vs baseline: 1.0057x; 1.0057x over previous
//
#include <hip/hip_runtime.h>

typedef float f32x4  __attribute__((ext_vector_type(4)));
typedef float f32x16 __attribute__((ext_vector_type(16)));
typedef short s16x8  __attribute__((ext_vector_type(8)));

constexpr int NL  = 31;
constexpr int BB  = 64;
constexpr int TT  = 512;
constexpr int DD  = 768;
constexpr int RTOT = BB * TT;
constexpr int IDX_EOS = 29;
constexpr int IDX_BOS = 30;
constexpr float LOG2E = 1.4426950408889634f;
constexpr float LN2F  = 0.6931471805599453f;

union Frag8 { unsigned u[4]; s16x8 s; };

__device__ inline unsigned pk2(float a, float b) {
  unsigned ua = __float_as_uint(a), ub = __float_as_uint(b);
  ua = (ua + 0x7fffu + ((ua >> 16) & 1u)) >> 16;   // RNE f32->bf16
  ub = (ub + 0x7fffu + ((ub >> 16) & 1u)) >> 16;
  return ua | (ub << 16);
}
__device__ inline unsigned short bf16r(float a) {
  unsigned ua = __float_as_uint(a);
  return (unsigned short)((ua + 0x7fffu + ((ua >> 16) & 1u)) >> 16);
}

__device__ inline float bfly_max32(float v) {
#define STEPM(K) { float o = __int_as_float(__builtin_amdgcn_ds_swizzle(__float_as_int(v), ((K) << 10) | 0x1f)); v = fmaxf(v, o); }
  STEPM(1) STEPM(2) STEPM(4) STEPM(8) STEPM(16)
#undef STEPM
  return v;
}
__device__ inline float bfly_sum32(float v) {
#define STEPS(K) { float o = __int_as_float(__builtin_amdgcn_ds_swizzle(__float_as_int(v), ((K) << 10) | 0x1f)); v = v + o; }
  STEPS(1) STEPS(2) STEPS(4) STEPS(8) STEPS(16)
#undef STEPS
  return v;
}

// ------------- K0: state_w f32 (31x768) -> bf16 padded (32x768) -------------
__global__ void k_prep(const float* __restrict__ sw, unsigned short* __restrict__ Bw) {
  for (int i = blockIdx.x * 256 + threadIdx.x; i < 32 * DD; i += 8 * 256)
    Bw[i] = (i < NL * DD) ? bf16r(sw[i]) : (unsigned short)0;
}

// ------------- K1: out_s = input @ state_w^T + bias (MFMA, LDS-staged) ------
// 64 rows/block, 512 blocks. K-loop BK=64, double-buffered LDS (stride 72
// shorts: breaks the 16-way bank conflict of stride 64 -> 2-way, free).
__global__ __launch_bounds__(256) void k_outs(
    const float* __restrict__ inp, const unsigned short* __restrict__ Bw,
    const float* __restrict__ sb, const float* __restrict__ msk,
    float* __restrict__ outs)
{
  __shared__ unsigned short As[2][64 * 72];
  int tid = threadIdx.x, wave = tid >> 6, lane = tid & 63;
  int quad = lane >> 4, l15 = lane & 15;
  int r0 = blockIdx.x * 64;
  int lrow = tid >> 4;                     // staging: row within 16-row pass
  const float* gsrc = inp + (size_t)r0 * DD + (tid & 15) * 4;

  f32x4 pre[4];
#pragma unroll
  for (int p = 0; p < 4; ++p)
    pre[p] = *(const f32x4*)(gsrc + (size_t)(p * 16 + lrow) * DD);

  f32x4 acc[2] = {};
  for (int kc = 0; kc < 12; ++kc) {
    unsigned* dstb = (unsigned*)As[kc & 1];
#pragma unroll
    for (int p = 0; p < 4; ++p) {
      int row = p * 16 + lrow;
      dstb[row * 36 + (tid & 15) * 2]     = pk2(pre[p][0], pre[p][1]);
      dstb[row * 36 + (tid & 15) * 2 + 1] = pk2(pre[p][2], pre[p][3]);
    }
    __syncthreads();
    if (kc < 11) {
      const float* g2 = gsrc + (kc + 1) * 64;
#pragma unroll
      for (int p = 0; p < 4; ++p)
        pre[p] = *(const f32x4*)(g2 + (size_t)(p * 16 + lrow) * DD);
    }
    const unsigned short* asb = As[kc & 1];
#pragma unroll
    for (int ks = 0; ks < 2; ++ks) {
      s16x8 af = *(const s16x8*)(asb + (wave * 16 + l15) * 72 + ks * 32 + quad * 8);
#pragma unroll
      for (int ct = 0; ct < 2; ++ct) {
        s16x8 bf = *(const s16x8*)(Bw + (ct * 16 + l15) * DD + kc * 64 + ks * 32 + quad * 8);
        acc[ct] = __builtin_amdgcn_mfma_f32_16x16x32_bf16(af, bf, acc[ct], 0, 0, 0);
      }
    }
    __syncthreads();
  }
#pragma unroll
  for (int ct = 0; ct < 2; ++ct) {
    int n = ct * 16 + l15;
    if (n >= NL) continue;
    float b = sb[n];
#pragma unroll
    for (int r = 0; r < 4; ++r) {
      int row = r0 + wave * 16 + quad * 4 + r;
      float v = acc[ct][r] + b;
      if (n == IDX_EOS && msk[row] == 0.f) v += 20000.f;
      outs[(size_t)row * NL + n] = v;
    }
  }
}

// ------------- K2: chunked scan — compose chunk transfer matrices -----------
// Unit = (batch b, chunk c): M_c = prod_{t in chunk} diag(U_t) W^T, via
// mfma_f32_32x32x16_bf16 (2 chained per step). D(col-fixed) -> B-frag
// (col-fixed) needs only a half-swap: 4 shfl_xor(·,32) of packed pairs.
__global__ __launch_bounds__(256) void k_chunk(
    const float* __restrict__ outs, const float* __restrict__ trans,
    float* __restrict__ Mout, float* __restrict__ Mscale)
{
  __shared__ float Ub[4][64 * 32];
  int tid = threadIdx.x, wave = tid >> 6, lane = tid & 63;
  int l = lane & 31, h = lane >> 5;
  int unit = blockIdx.x * 4 + wave;
  int b = unit >> 3, c = unit & 7;
  int t0 = c * 64;
  int nsteps = (c == 7) ? 63 : 64;         // t = t0+1 .. min(t0+64, 511)

  float* ub = Ub[wave];
  for (int idx = lane; idx < 2048; idx += 64) {
    int row = idx >> 5, col = idx & 31;
    float v = 0.f;
    if (col < NL && row < nsteps)
      v = exp2f(LOG2E * outs[((size_t)b * TT + t0 + 1 + row) * NL + col]);
    ub[idx] = v;
  }
  __syncthreads();

  Frag8 A1, A2, B1, B2;
#pragma unroll
  for (int m = 0; m < 4; ++m) {
    int k0 = 8 * h + 2 * m, k1 = k0 + 1;
    float a0 = (k0 < NL && l < NL) ? exp2f(LOG2E * trans[k0 * NL + l]) : 0.f;
    float a1 = (k1 < NL && l < NL) ? exp2f(LOG2E * trans[k1 * NL + l]) : 0.f;
    A1.u[m] = pk2(a0, a1);
    int k2 = 16 + k0, k3 = 16 + k1;
    float a2 = (k2 < NL && l < NL) ? exp2f(LOG2E * trans[k2 * NL + l]) : 0.f;
    float a3 = (k3 < NL && l < NL) ? exp2f(LOG2E * trans[k3 * NL + l]) : 0.f;
    A2.u[m] = pk2(a2, a3);
    B1.u[m] = ((k0 == l) ? 0x3f80u : 0u) | (((k1 == l) ? 0x3f80u : 0u) << 16);
    B2.u[m] = ((k2 == l) ? 0x3f80u : 0u) | (((k3 == l) ? 0x3f80u : 0u) << 16);
  }

  float M2 = 0.f;
  float E[16];
  for (int s = 0; s < nsteps; ++s) {
    const float* us = ub + s * 32 + 4 * h;
    f32x4 u0 = *(const f32x4*)(us);
    f32x4 u1 = *(const f32x4*)(us + 8);
    f32x4 u2 = *(const f32x4*)(us + 16);
    f32x4 u3 = *(const f32x4*)(us + 24);
    f32x16 D = {};
    D = __builtin_amdgcn_mfma_f32_32x32x16_bf16(A1.s, B1.s, D, 0, 0, 0);
    D = __builtin_amdgcn_mfma_f32_32x32x16_bf16(A2.s, B2.s, D, 0, 0, 0);
    // row(reg r) = (r&3) + 8*(r>>2) + 4h  ->  U value = us[8*(r>>2) + (r&3)]
#pragma unroll
    for (int jj = 0; jj < 4; ++jj) {
      E[jj]      = D[jj]      * u0[jj];
      E[4 + jj]  = D[4 + jj]  * u1[jj];
      E[8 + jj]  = D[8 + jj]  * u2[jj];
      E[12 + jj] = D[12 + jj] * u3[jj];
    }
    if ((s & 7) == 7) {
      float m = E[0];
#pragma unroll
      for (int r = 1; r < 16; ++r) m = fmaxf(m, E[r]);
      m = bfly_max32(m);
      m = fmaxf(m, __shfl_xor(m, 32));
      float lg = truncf(log2f(m));
      M2 += lg;
      float sc = exp2f(-lg);
#pragma unroll
      for (int r = 0; r < 16; ++r) E[r] *= sc;
    }
    if (s + 1 < nsteps) {
      unsigned o1a = pk2(E[4 * h], E[4 * h + 1]), o1b = pk2(E[4 * h + 2], E[4 * h + 3]);
      unsigned o2a = pk2(E[8 + 4 * h], E[8 + 4 * h + 1]), o2b = pk2(E[8 + 4 * h + 2], E[8 + 4 * h + 3]);
      int hb = 4 * (1 - h);
      unsigned s1a = pk2(E[hb], E[hb + 1]),         s1b = pk2(E[hb + 2], E[hb + 3]);
      unsigned s2a = pk2(E[8 + hb], E[8 + hb + 1]), s2b = pk2(E[8 + hb + 2], E[8 + hb + 3]);
      unsigned r1a = __shfl_xor((int)s1a, 32), r1b = __shfl_xor((int)s1b, 32);
      unsigned r2a = __shfl_xor((int)s2a, 32), r2b = __shfl_xor((int)s2b, 32);
      if (h == 0) {
        B1.u[0] = o1a; B1.u[1] = o1b; B1.u[2] = r1a; B1.u[3] = r1b;
        B2.u[0] = o2a; B2.u[1] = o2b; B2.u[2] = r2a; B2.u[3] = r2b;
      } else {
        B1.u[0] = r1a; B1.u[1] = r1b; B1.u[2] = o1a; B1.u[3] = o1b;
        B2.u[0] = r2a; B2.u[1] = r2b; B2.u[2] = o2a; B2.u[3] = o2b;
      }
    }
  }
  float* mo = Mout + (size_t)unit * 1024;
#pragma unroll
  for (int r = 0; r < 16; ++r) {
    int row = (r & 3) + 8 * (r >> 2) + 4 * h;
    mo[row * 32 + l] = E[r];
  }
  if (lane == 0) Mscale[unit] = M2;
}

// ------------- K3: combine 8 chunk matrices per batch -> lse ----------------
__global__ __launch_bounds__(256) void k_combine(
    const float* __restrict__ outs, const float* __restrict__ trans,
    const float* __restrict__ Mmat, const float* __restrict__ Mscale,
    float* __restrict__ ws_lse)
{
  int tid = threadIdx.x, wave = tid >> 6, lane = tid & 63, l = lane & 31;
  int b = blockIdx.x * 4 + wave;
  float p = (l < NL) ? exp2f(LOG2E * (trans[IDX_BOS * NL + l] + outs[(size_t)b * TT * NL + l])) : 0.f;
  float M2 = 0.f;
  for (int c = 0; c < 8; ++c) {
    const float* mr = Mmat + (size_t)(b * 8 + c) * 1024 + l * 32;
    f32x4 rv[8];
#pragma unroll
    for (int q = 0; q < 8; ++q) rv[q] = *(const f32x4*)(mr + q * 4);
    int pb = __float_as_int(p);
    float a0 = 0.f, a1 = 0.f, a2 = 0.f, a3 = 0.f;
#define BC(I, AC) { float pv = __int_as_float(__builtin_amdgcn_ds_swizzle(pb, (I) << 5)); AC = fmaf(rv[(I) / 4][(I) & 3], pv, AC); }
    BC(0,a0)  BC(1,a1)  BC(2,a2)  BC(3,a3)
    BC(4,a0)  BC(5,a1)  BC(6,a2)  BC(7,a3)
    BC(8,a0)  BC(9,a1)  BC(10,a2) BC(11,a3)
    BC(12,a0) BC(13,a1) BC(14,a2) BC(15,a3)
    BC(16,a0) BC(17,a1) BC(18,a2) BC(19,a3)
    BC(20,a0) BC(21,a1) BC(22,a2) BC(23,a3)
    BC(24,a0) BC(25,a1) BC(26,a2) BC(27,a3)
    BC(28,a0) BC(29,a1) BC(30,a2) BC(31,a3)
#undef BC
    float acc = (a0 + a1) + (a2 + a3);
    M2 += Mscale[b * 8 + c];
    float m = bfly_max32(acc);
    float lg = truncf(log2f(m));
    M2 += lg;
    p = acc * exp2f(-lg);
  }
  float We = (l < NL) ? exp2f(LOG2E * trans[l * NL + IDX_EOS]) : 0.f;
  float v = bfly_sum32(p * We);
  if (lane == 0) ws_lse[b] = LN2F * (M2 + log2f(v));
}

// ------------- K4: energy write + tgt_energy --------------------------------
__global__ __launch_bounds__(256) void k_energy(
    const float* __restrict__ outs, const float* __restrict__ trans,
    const int* __restrict__ target, float* __restrict__ energy,
    float* __restrict__ ws_tgt)
{
  __shared__ float tr[961];
  __shared__ float oshm[32 * NL];
  int r0 = blockIdx.x * 32;
  for (int idx = threadIdx.x; idx < 961; idx += 256) tr[idx] = trans[idx];
  for (int idx = threadIdx.x; idx < 32 * NL; idx += 256)
    oshm[idx] = outs[(size_t)r0 * NL + idx];
  __syncthreads();

  if (threadIdx.x < 32) {
    int r = r0 + threadIdx.x;
    int tgt = target[r];
    int prv = ((r & (TT - 1)) == 0) ? IDX_BOS : target[r - 1];
    float c = tr[prv * NL + tgt] + oshm[threadIdx.x * NL + tgt];
    for (int off = 16; off; off >>= 1) c += __shfl_down(c, off, 32);
    if (threadIdx.x == 0) atomicAdd(&ws_tgt[r0 / TT], c);
  }

  int e0 = threadIdx.x, e1 = e0 + 256, e2 = e0 + 512, e3 = e0 + 768;
  float t0 = tr[e0], t1 = tr[e1], t2 = tr[e2];
  bool w3 = (e3 < 961);
  float t3 = w3 ? tr[e3] : 0.f;
  int j0 = e0 % 31, j1 = e1 % 31, j2 = e2 % 31, j3 = e3 % 31;
  for (int rr = 0; rr < 32; ++rr) {
    const float* ob = &oshm[rr * NL];
    float* dst = energy + (size_t)(r0 + rr) * 961;
    dst[e0] = t0 + ob[j0];
    dst[e1] = t1 + ob[j1];
    dst[e2] = t2 + ob[j2];
    if (w3) dst[e3] = t3 + ob[j3];
  }
}

// ------------- K5: loss = lse - tgt -----------------------------------------
__global__ void k_loss(const float* __restrict__ ws_lse,
                       const float* __restrict__ ws_tgt,
                       float* __restrict__ loss)
{
  int b = threadIdx.x;
  if (b < BB) loss[b] = ws_lse[b] - ws_tgt[b];
}

extern "C" void kernel_launch(void* const* d_in, const int* in_sizes, int n_in,
                              void* d_out, int out_size, void* d_ws, size_t ws_size,
                              hipStream_t stream) {
  const float* inp   = (const float*)d_in[0];   // (64,512,768) f32
  const int*   tgt   = (const int*)d_in[1];     // (64,512) int
  const float* msk   = (const float*)d_in[2];   // (64,512) f32
  const float* sw    = (const float*)d_in[3];   // (31,768) f32
  const float* sb    = (const float*)d_in[4];   // (31,) f32
  const float* trans = (const float*)d_in[5];   // (31,31) f32

  float* out    = (float*)d_out;
  float* loss   = out;
  float* energy = out + BB;
  // scratch carved from the energy region (overwritten later, stream-ordered):
  float* Mmat = energy;                               // 512*1024 f32
  unsigned short* Bw = (unsigned short*)(energy + 524288);  // 32*768 bf16

  float* outs   = (float*)d_ws;                 // 32768*31 f32
  float* ws_tgt = outs + (size_t)RTOT * NL;     // 64
  float* ws_lse = ws_tgt + 64;                  // 64
  float* Mscale = ws_lse + 64;                  // 512

  hipMemsetAsync(ws_tgt, 0, 64 * sizeof(float), stream);
  k_prep<<<8, 256, 0, stream>>>(sw, Bw);
  k_outs<<<RTOT / 64, 256, 0, stream>>>(inp, Bw, sb, msk, outs);
  k_chunk<<<128, 256, 0, stream>>>(outs, trans, Mmat, Mscale);
  k_combine<<<16, 256, 0, stream>>>(outs, trans, Mmat, Mscale, ws_lse);
  k_energy<<<RTOT / 32, 256, 0, stream>>>(outs, trans, tgt, energy, ws_tgt);
  k_loss<<<1, 64, 0, stream>>>(ws_lse, ws_tgt, loss);
}

// Round 3
// 328.579 us; speedup vs baseline: 1.2034x; 1.1966x over previous
//
#include <hip/hip_runtime.h>

typedef float f32x4  __attribute__((ext_vector_type(4)));
typedef float f32x16 __attribute__((ext_vector_type(16)));
typedef short s16x8  __attribute__((ext_vector_type(8)));

constexpr int NL  = 31;
constexpr int BB  = 64;
constexpr int TT  = 512;
constexpr int DD  = 768;
constexpr int RTOT = BB * TT;
constexpr int IDX_EOS = 29;
constexpr int IDX_BOS = 30;
constexpr float LOG2E = 1.4426950408889634f;
constexpr float LN2F  = 0.6931471805599453f;

union Frag8 { unsigned u[4]; s16x8 s; };

__device__ inline unsigned pk2(float a, float b) {
  unsigned ua = __float_as_uint(a), ub = __float_as_uint(b);
  ua = (ua + 0x7fffu + ((ua >> 16) & 1u)) >> 16;   // RNE f32->bf16
  ub = (ub + 0x7fffu + ((ub >> 16) & 1u)) >> 16;
  return ua | (ub << 16);
}
__device__ inline unsigned short bf16r(float a) {
  unsigned ua = __float_as_uint(a);
  return (unsigned short)((ua + 0x7fffu + ((ua >> 16) & 1u)) >> 16);
}

__device__ inline float bfly_max32(float v) {
#define STEPM(K) { float o = __int_as_float(__builtin_amdgcn_ds_swizzle(__float_as_int(v), ((K) << 10) | 0x1f)); v = fmaxf(v, o); }
  STEPM(1) STEPM(2) STEPM(4) STEPM(8) STEPM(16)
#undef STEPM
  return v;
}
__device__ inline float bfly_sum32(float v) {
#define STEPS(K) { float o = __int_as_float(__builtin_amdgcn_ds_swizzle(__float_as_int(v), ((K) << 10) | 0x1f)); v = v + o; }
  STEPS(1) STEPS(2) STEPS(4) STEPS(8) STEPS(16)
#undef STEPS
  return v;
}

// D(C-layout, f32[16]) -> B-frag(bf16) half-swap repack [R2-verified]
__device__ inline void repack(const float E[16], int h, Frag8& B1, Frag8& B2) {
  unsigned o1a = pk2(E[4 * h], E[4 * h + 1]), o1b = pk2(E[4 * h + 2], E[4 * h + 3]);
  unsigned o2a = pk2(E[8 + 4 * h], E[8 + 4 * h + 1]), o2b = pk2(E[8 + 4 * h + 2], E[8 + 4 * h + 3]);
  int hb = 4 * (1 - h);
  unsigned s1a = pk2(E[hb], E[hb + 1]),         s1b = pk2(E[hb + 2], E[hb + 3]);
  unsigned s2a = pk2(E[8 + hb], E[8 + hb + 1]), s2b = pk2(E[8 + hb + 2], E[8 + hb + 3]);
  unsigned r1a = __shfl_xor((int)s1a, 32), r1b = __shfl_xor((int)s1b, 32);
  unsigned r2a = __shfl_xor((int)s2a, 32), r2b = __shfl_xor((int)s2b, 32);
  if (h == 0) {
    B1.u[0] = o1a; B1.u[1] = o1b; B1.u[2] = r1a; B1.u[3] = r1b;
    B2.u[0] = o2a; B2.u[1] = o2b; B2.u[2] = r2a; B2.u[3] = r2b;
  } else {
    B1.u[0] = r1a; B1.u[1] = r1b; B1.u[2] = o1a; B1.u[3] = o1b;
    B2.u[0] = r2a; B2.u[1] = r2b; B2.u[2] = o2a; B2.u[3] = o2b;
  }
}

__device__ inline float renorm16(float E[16], float& Sacc) {
  float m = E[0];
#pragma unroll
  for (int r = 1; r < 16; ++r) m = fmaxf(m, E[r]);
  m = bfly_max32(m);
  m = fmaxf(m, __shfl_xor(m, 32));
  float lg = truncf(log2f(m));
  Sacc += lg;
  float sc = exp2f(-lg);
#pragma unroll
  for (int r = 0; r < 16; ++r) E[r] *= sc;
  return m;
}

// load LEFT matrix (row-major 32x32 f32) as A-frags: A[m][k], m = lane&31
__device__ inline void load_A(const float* M, int l, int h, Frag8& A1, Frag8& A2) {
  const float* row = M + (l & 31) * 32 + 8 * h;
  f32x4 a = *(const f32x4*)(row);        // k = 8h..8h+3
  f32x4 b = *(const f32x4*)(row + 4);    // k = 8h+4..8h+7
  f32x4 c = *(const f32x4*)(row + 16);   // k = 16+8h..
  f32x4 d = *(const f32x4*)(row + 20);
  A1.u[0] = pk2(a[0], a[1]); A1.u[1] = pk2(a[2], a[3]);
  A1.u[2] = pk2(b[0], b[1]); A1.u[3] = pk2(b[2], b[3]);
  A2.u[0] = pk2(c[0], c[1]); A2.u[1] = pk2(c[2], c[3]);
  A2.u[2] = pk2(d[0], d[1]); A2.u[3] = pk2(d[2], d[3]);
}

// load RIGHT matrix (row-major 32x32 f32) as B-frags: B[k][n], n = lane&31
__device__ inline void load_B(const float* M, int l, int h, Frag8& B1, Frag8& B2) {
  int nn = l & 31;
#pragma unroll
  for (int m = 0; m < 4; ++m) {
    int k = 8 * h + 2 * m;
    B1.u[m] = pk2(M[k * 32 + nn],        M[(k + 1) * 32 + nn]);
    B2.u[m] = pk2(M[(k + 16) * 32 + nn], M[(k + 17) * 32 + nn]);
  }
}

// ------------- K0: state_w f32 (31x768) -> bf16 padded (32x768) -------------
__global__ void k_prep(const float* __restrict__ sw, unsigned short* __restrict__ Bw) {
  for (int i = blockIdx.x * 256 + threadIdx.x; i < 32 * DD; i += 8 * 256)
    Bw[i] = (i < NL * DD) ? bf16r(sw[i]) : (unsigned short)0;
}

// ------------- K1: out_s = input @ state_w^T + bias (MFMA, LDS-staged) ------
__global__ __launch_bounds__(256) void k_outs(
    const float* __restrict__ inp, const unsigned short* __restrict__ Bw,
    const float* __restrict__ sb, const float* __restrict__ msk,
    float* __restrict__ outs)
{
  __shared__ unsigned short As[2][64 * 72];
  int tid = threadIdx.x, wave = tid >> 6, lane = tid & 63;
  int quad = lane >> 4, l15 = lane & 15;
  int r0 = blockIdx.x * 64;
  int lrow = tid >> 4;
  const float* gsrc = inp + (size_t)r0 * DD + (tid & 15) * 4;

  f32x4 pre[4];
#pragma unroll
  for (int p = 0; p < 4; ++p)
    pre[p] = *(const f32x4*)(gsrc + (size_t)(p * 16 + lrow) * DD);

  f32x4 acc[2] = {};
  for (int kc = 0; kc < 12; ++kc) {
    unsigned* dstb = (unsigned*)As[kc & 1];
#pragma unroll
    for (int p = 0; p < 4; ++p) {
      int row = p * 16 + lrow;
      dstb[row * 36 + (tid & 15) * 2]     = pk2(pre[p][0], pre[p][1]);
      dstb[row * 36 + (tid & 15) * 2 + 1] = pk2(pre[p][2], pre[p][3]);
    }
    __syncthreads();
    if (kc < 11) {
      const float* g2 = gsrc + (kc + 1) * 64;
#pragma unroll
      for (int p = 0; p < 4; ++p)
        pre[p] = *(const f32x4*)(g2 + (size_t)(p * 16 + lrow) * DD);
    }
    const unsigned short* asb = As[kc & 1];
#pragma unroll
    for (int ks = 0; ks < 2; ++ks) {
      s16x8 af = *(const s16x8*)(asb + (wave * 16 + l15) * 72 + ks * 32 + quad * 8);
#pragma unroll
      for (int ct = 0; ct < 2; ++ct) {
        s16x8 bf = *(const s16x8*)(Bw + (ct * 16 + l15) * DD + kc * 64 + ks * 32 + quad * 8);
        acc[ct] = __builtin_amdgcn_mfma_f32_16x16x32_bf16(af, bf, acc[ct], 0, 0, 0);
      }
    }
    __syncthreads();
  }
#pragma unroll
  for (int ct = 0; ct < 2; ++ct) {
    int n = ct * 16 + l15;
    if (n >= NL) continue;
    float b = sb[n];
#pragma unroll
    for (int r = 0; r < 4; ++r) {
      int row = r0 + wave * 16 + quad * 4 + r;
      float v = acc[ct][r] + b;
      if (n == IDX_EOS && msk[row] == 0.f) v += 20000.f;
      outs[(size_t)row * NL + n] = v;
    }
  }
}

// ------------- K2: 8-step segment transfer matrices -------------------------
// unit = b*64 + c; steps t = 1+8c .. min(1+8c+8, 512)-1. One wave per unit.
__global__ __launch_bounds__(256) void k_seg(
    const float* __restrict__ outs, const float* __restrict__ trans,
    float* __restrict__ Mseg, float* __restrict__ Sseg)
{
  __shared__ float Ub[4][8 * 32];
  int tid = threadIdx.x, wave = tid >> 6, lane = tid & 63;
  int l = lane & 31, h = lane >> 5;
  int unit = blockIdx.x * 4 + wave;
  int b = unit >> 6, c = unit & 63;
  int t0 = 1 + c * 8;
  int n = (c == 63) ? 7 : 8;

  float* ub = Ub[wave];
#pragma unroll
  for (int it = 0; it < 4; ++it) {
    int idx = lane + it * 64;
    int row = idx >> 5, col = idx & 31;
    float v = 0.f;
    if (col < NL && row < n)
      v = exp2f(LOG2E * outs[((size_t)b * TT + t0 + row) * NL + col]);
    ub[idx] = v;
  }
  __syncthreads();

  Frag8 A1, A2, B1, B2;
#pragma unroll
  for (int m = 0; m < 4; ++m) {
    int k0 = 8 * h + 2 * m, k1 = k0 + 1;
    float a0 = (k0 < NL && l < NL) ? exp2f(LOG2E * trans[k0 * NL + l]) : 0.f;
    float a1 = (k1 < NL && l < NL) ? exp2f(LOG2E * trans[k1 * NL + l]) : 0.f;
    A1.u[m] = pk2(a0, a1);
    int k2 = 16 + k0, k3 = 16 + k1;
    float a2 = (k2 < NL && l < NL) ? exp2f(LOG2E * trans[k2 * NL + l]) : 0.f;
    float a3 = (k3 < NL && l < NL) ? exp2f(LOG2E * trans[k3 * NL + l]) : 0.f;
    A2.u[m] = pk2(a2, a3);
    B1.u[m] = ((k0 == l) ? 0x3f80u : 0u) | (((k1 == l) ? 0x3f80u : 0u) << 16);
    B2.u[m] = ((k2 == l) ? 0x3f80u : 0u) | (((k3 == l) ? 0x3f80u : 0u) << 16);
  }

  float E[16];
  for (int s = 0; s < n; ++s) {
    const float* us = ub + s * 32 + 4 * h;
    f32x4 u0 = *(const f32x4*)(us);
    f32x4 u1 = *(const f32x4*)(us + 8);
    f32x4 u2 = *(const f32x4*)(us + 16);
    f32x4 u3 = *(const f32x4*)(us + 24);
    f32x16 D = {};
    D = __builtin_amdgcn_mfma_f32_32x32x16_bf16(A1.s, B1.s, D, 0, 0, 0);
    D = __builtin_amdgcn_mfma_f32_32x32x16_bf16(A2.s, B2.s, D, 0, 0, 0);
#pragma unroll
    for (int jj = 0; jj < 4; ++jj) {
      E[jj]      = D[jj]      * u0[jj];
      E[4 + jj]  = D[4 + jj]  * u1[jj];
      E[8 + jj]  = D[8 + jj]  * u2[jj];
      E[12 + jj] = D[12 + jj] * u3[jj];
    }
    if (s + 1 < n) repack(E, h, B1, B2);
  }
  float S = 0.f;
  renorm16(E, S);
  float* mo = Mseg + (size_t)unit * 1024;
#pragma unroll
  for (int r = 0; r < 16; ++r) {
    int row = (r & 3) + 8 * (r >> 2) + 4 * h;
    mo[row * 32 + l] = E[r];
  }
  if (lane == 0) Sseg[unit] = S;
}

// ------------- K3: quad products: Q = M3*M2*M1*M0 ---------------------------
__global__ __launch_bounds__(256) void k_tree1(
    const float* __restrict__ Mseg, const float* __restrict__ Sseg,
    float* __restrict__ Mq, float* __restrict__ Sq)
{
  int tid = threadIdx.x, wave = tid >> 6, lane = tid & 63;
  int l = lane & 31, h = lane >> 5;
  int unit = blockIdx.x * 4 + wave;                 // (b,q): unit = b*16+q
  const float* base = Mseg + (size_t)unit * 4096;   // 4 matrices
  Frag8 A1, A2, B1, B2;
  load_B(base, l, h, B1, B2);
  float S = Sseg[unit * 4] + Sseg[unit * 4 + 1] + Sseg[unit * 4 + 2] + Sseg[unit * 4 + 3];
  float E[16];
#pragma unroll
  for (int i = 1; i < 4; ++i) {
    load_A(base + i * 1024, l, h, A1, A2);
    f32x16 D = {};
    D = __builtin_amdgcn_mfma_f32_32x32x16_bf16(A1.s, B1.s, D, 0, 0, 0);
    D = __builtin_amdgcn_mfma_f32_32x32x16_bf16(A2.s, B2.s, D, 0, 0, 0);
#pragma unroll
    for (int r = 0; r < 16; ++r) E[r] = D[r];
    if (i < 3) repack(E, h, B1, B2);
  }
  renorm16(E, S);
  float* mo = Mq + (size_t)unit * 1024;
#pragma unroll
  for (int r = 0; r < 16; ++r) {
    int row = (r & 3) + 8 * (r >> 2) + 4 * h;
    mo[row * 32 + l] = E[r];
  }
  if (lane == 0) Sq[unit] = S;
}

// ------------- K4: per-batch final product + lse ----------------------------
__global__ __launch_bounds__(256) void k_tree2(
    const float* __restrict__ outs, const float* __restrict__ trans,
    const float* __restrict__ Mq, const float* __restrict__ Sq,
    float* __restrict__ ws_lse)
{
  int tid = threadIdx.x, wave = tid >> 6, lane = tid & 63;
  int l = lane & 31, h = lane >> 5;
  int b = blockIdx.x * 4 + wave;
  const float* base = Mq + (size_t)b * 16384;       // 16 matrices
  Frag8 A1, A2, B1, B2;
  load_B(base, l, h, B1, B2);
  float S = 0.f;
#pragma unroll
  for (int q = 0; q < 16; ++q) S += Sq[b * 16 + q];
  float E[16];
  for (int i = 1; i < 16; ++i) {
    load_A(base + i * 1024, l, h, A1, A2);
    f32x16 D = {};
    D = __builtin_amdgcn_mfma_f32_32x32x16_bf16(A1.s, B1.s, D, 0, 0, 0);
    D = __builtin_amdgcn_mfma_f32_32x32x16_bf16(A2.s, B2.s, D, 0, 0, 0);
#pragma unroll
    for (int r = 0; r < 16; ++r) E[r] = D[r];
    if ((i & 3) == 3) renorm16(E, S);               // i = 3,7,11,15
    if (i < 15) repack(E, h, B1, B2);
  }
  // finalize: p_final = E * p0 (2^S scaled); lse = ln2*(S + log2(sum We*p))
  float p0 = (l < NL) ? exp2f(LOG2E * (trans[IDX_BOS * NL + l] + outs[(size_t)b * TT * NL + l])) : 0.f;
  float sum_h = 0.f;
#pragma unroll
  for (int r = 0; r < 16; ++r) {
    float s = bfly_sum32(E[r] * p0);
    int row = (r & 3) + 8 * (r >> 2) + 4 * h;
    float We = (row < NL) ? exp2f(LOG2E * trans[row * NL + IDX_EOS]) : 0.f;
    sum_h += s * We;
  }
  float tot = sum_h + __shfl_xor(sum_h, 32);
  if (lane == 0) ws_lse[b] = LN2F * (S + log2f(tot));
}

// ------------- K5: energy write + tgt_energy --------------------------------
__global__ __launch_bounds__(256) void k_energy(
    const float* __restrict__ outs, const float* __restrict__ trans,
    const int* __restrict__ target, float* __restrict__ energy,
    float* __restrict__ ws_tgt)
{
  __shared__ float tr[961];
  __shared__ float oshm[32 * NL];
  int r0 = blockIdx.x * 32;
  for (int idx = threadIdx.x; idx < 961; idx += 256) tr[idx] = trans[idx];
  for (int idx = threadIdx.x; idx < 32 * NL; idx += 256)
    oshm[idx] = outs[(size_t)r0 * NL + idx];
  __syncthreads();

  if (threadIdx.x < 32) {
    int r = r0 + threadIdx.x;
    int tgt = target[r];
    int prv = ((r & (TT - 1)) == 0) ? IDX_BOS : target[r - 1];
    float c = tr[prv * NL + tgt] + oshm[threadIdx.x * NL + tgt];
    for (int off = 16; off; off >>= 1) c += __shfl_down(c, off, 32);
    if (threadIdx.x == 0) atomicAdd(&ws_tgt[r0 / TT], c);
  }

  int e0 = threadIdx.x, e1 = e0 + 256, e2 = e0 + 512, e3 = e0 + 768;
  float t0 = tr[e0], t1 = tr[e1], t2 = tr[e2];
  bool w3 = (e3 < 961);
  float t3 = w3 ? tr[e3] : 0.f;
  int j0 = e0 % 31, j1 = e1 % 31, j2 = e2 % 31, j3 = e3 % 31;
  for (int rr = 0; rr < 32; ++rr) {
    const float* ob = &oshm[rr * NL];
    float* dst = energy + (size_t)(r0 + rr) * 961;
    dst[e0] = t0 + ob[j0];
    dst[e1] = t1 + ob[j1];
    dst[e2] = t2 + ob[j2];
    if (w3) dst[e3] = t3 + ob[j3];
  }
}

// ------------- K6: loss = lse - tgt -----------------------------------------
__global__ void k_loss(const float* __restrict__ ws_lse,
                       const float* __restrict__ ws_tgt,
                       float* __restrict__ loss)
{
  int b = threadIdx.x;
  if (b < BB) loss[b] = ws_lse[b] - ws_tgt[b];
}

extern "C" void kernel_launch(void* const* d_in, const int* in_sizes, int n_in,
                              void* d_out, int out_size, void* d_ws, size_t ws_size,
                              hipStream_t stream) {
  const float* inp   = (const float*)d_in[0];   // (64,512,768) f32
  const int*   tgt   = (const int*)d_in[1];     // (64,512) int
  const float* msk   = (const float*)d_in[2];   // (64,512) f32
  const float* sw    = (const float*)d_in[3];   // (31,768) f32
  const float* sb    = (const float*)d_in[4];   // (31,) f32
  const float* trans = (const float*)d_in[5];   // (31,31) f32

  float* out    = (float*)d_out;
  float* loss   = out;
  float* energy = out + BB;
  // scratch carved from the energy region (consumed before k_energy writes):
  float* Mseg = energy;                                   // 4096*1024 f32
  float* Mq   = energy + (size_t)4096 * 1024;             // 1024*1024 f32
  float* Sseg = energy + (size_t)4096 * 1024 + 1024 * 1024;  // 4096 f32
  float* Sq   = Sseg + 4096;                              // 1024 f32
  unsigned short* Bw = (unsigned short*)(Sq + 1024);      // 32*768 bf16

  float* outs   = (float*)d_ws;                 // 32768*31 f32
  float* ws_tgt = outs + (size_t)RTOT * NL;     // 64
  float* ws_lse = ws_tgt + 64;                  // 64

  hipMemsetAsync(ws_tgt, 0, 64 * sizeof(float), stream);
  k_prep<<<8, 256, 0, stream>>>(sw, Bw);
  k_outs<<<RTOT / 64, 256, 0, stream>>>(inp, Bw, sb, msk, outs);
  k_seg<<<1024, 256, 0, stream>>>(outs, trans, Mseg, Sseg);
  k_tree1<<<256, 256, 0, stream>>>(Mseg, Sseg, Mq, Sq);
  k_tree2<<<16, 256, 0, stream>>>(outs, trans, Mq, Sq, ws_lse);
  k_energy<<<RTOT / 32, 256, 0, stream>>>(outs, trans, tgt, energy, ws_tgt);
  k_loss<<<1, 64, 0, stream>>>(ws_lse, ws_tgt, loss);
}

// Round 4
// 299.766 us; speedup vs baseline: 1.3191x; 1.0961x over previous
//
#include <hip/hip_runtime.h>

typedef float f32x4  __attribute__((ext_vector_type(4)));
typedef float f32x16 __attribute__((ext_vector_type(16)));
typedef short s16x8  __attribute__((ext_vector_type(8)));

constexpr int NL  = 31;
constexpr int BB  = 64;
constexpr int TT  = 512;
constexpr int DD  = 768;
constexpr int RTOT = BB * TT;
constexpr int IDX_EOS = 29;
constexpr int IDX_BOS = 30;
constexpr float LOG2E = 1.4426950408889634f;
constexpr float LN2F  = 0.6931471805599453f;

union Frag8 { unsigned u[4]; s16x8 s; };

__device__ inline unsigned pk2(float a, float b) {
  unsigned ua = __float_as_uint(a), ub = __float_as_uint(b);
  ua = (ua + 0x7fffu + ((ua >> 16) & 1u)) >> 16;   // RNE f32->bf16
  ub = (ub + 0x7fffu + ((ub >> 16) & 1u)) >> 16;
  return ua | (ub << 16);
}
__device__ inline unsigned short bf16r(float a) {
  unsigned ua = __float_as_uint(a);
  return (unsigned short)((ua + 0x7fffu + ((ua >> 16) & 1u)) >> 16);
}

__device__ inline float bfly_max32(float v) {
#define STEPM(K) { float o = __int_as_float(__builtin_amdgcn_ds_swizzle(__float_as_int(v), ((K) << 10) | 0x1f)); v = fmaxf(v, o); }
  STEPM(1) STEPM(2) STEPM(4) STEPM(8) STEPM(16)
#undef STEPM
  return v;
}
__device__ inline float bfly_sum32(float v) {
#define STEPS(K) { float o = __int_as_float(__builtin_amdgcn_ds_swizzle(__float_as_int(v), ((K) << 10) | 0x1f)); v = v + o; }
  STEPS(1) STEPS(2) STEPS(4) STEPS(8) STEPS(16)
#undef STEPS
  return v;
}

// D(C-layout, f32[16]) -> B-frag(bf16) half-swap repack [R2-verified]
__device__ inline void repack(const float E[16], int h, Frag8& B1, Frag8& B2) {
  unsigned o1a = pk2(E[4 * h], E[4 * h + 1]), o1b = pk2(E[4 * h + 2], E[4 * h + 3]);
  unsigned o2a = pk2(E[8 + 4 * h], E[8 + 4 * h + 1]), o2b = pk2(E[8 + 4 * h + 2], E[8 + 4 * h + 3]);
  int hb = 4 * (1 - h);
  unsigned s1a = pk2(E[hb], E[hb + 1]),         s1b = pk2(E[hb + 2], E[hb + 3]);
  unsigned s2a = pk2(E[8 + hb], E[8 + hb + 1]), s2b = pk2(E[8 + hb + 2], E[8 + hb + 3]);
  unsigned r1a = __shfl_xor((int)s1a, 32), r1b = __shfl_xor((int)s1b, 32);
  unsigned r2a = __shfl_xor((int)s2a, 32), r2b = __shfl_xor((int)s2b, 32);
  if (h == 0) {
    B1.u[0] = o1a; B1.u[1] = o1b; B1.u[2] = r1a; B1.u[3] = r1b;
    B2.u[0] = o2a; B2.u[1] = o2b; B2.u[2] = r2a; B2.u[3] = r2b;
  } else {
    B1.u[0] = r1a; B1.u[1] = r1b; B1.u[2] = o1a; B1.u[3] = o1b;
    B2.u[0] = r2a; B2.u[1] = r2b; B2.u[2] = o2a; B2.u[3] = o2b;
  }
}

__device__ inline void renorm16(float E[16], float& Sacc) {
  float m = E[0];
#pragma unroll
  for (int r = 1; r < 16; ++r) m = fmaxf(m, E[r]);
  m = bfly_max32(m);
  m = fmaxf(m, __shfl_xor(m, 32));
  float lg = truncf(log2f(m));
  Sacc += lg;
  float sc = exp2f(-lg);
#pragma unroll
  for (int r = 0; r < 16; ++r) E[r] *= sc;
}

// bf16 row-major 32x32 matrix -> A-frags (A[m][k], m = lane&31)
__device__ inline void load_A16(const unsigned short* M, int l, int h, Frag8& A1, Frag8& A2) {
  A1.s = *(const s16x8*)(M + l * 32 + 8 * h);
  A2.s = *(const s16x8*)(M + l * 32 + 16 + 8 * h);
}
// bf16 row-major 32x32 matrix -> B-frags (B[k][n], n = lane&31)
__device__ inline void load_B16(const unsigned short* M, int l, int h, Frag8& B1, Frag8& B2) {
#pragma unroll
  for (int m = 0; m < 4; ++m) {
    int k = 8 * h + 2 * m;
    unsigned lo0 = M[k * 32 + l],        hi0 = M[(k + 1) * 32 + l];
    unsigned lo1 = M[(k + 16) * 32 + l], hi1 = M[(k + 17) * 32 + l];
    B1.u[m] = lo0 | (hi0 << 16);
    B2.u[m] = lo1 | (hi1 << 16);
  }
}

// ------------- K0: state_w -> bf16 padded; zero ws_tgt ----------------------
__global__ void k_prep(const float* __restrict__ sw, unsigned short* __restrict__ Bw,
                       float* __restrict__ ws_tgt) {
  if (blockIdx.x == 0 && threadIdx.x < BB) ws_tgt[threadIdx.x] = 0.f;
  for (int i = blockIdx.x * 256 + threadIdx.x; i < 32 * DD; i += 8 * 256)
    Bw[i] = (i < NL * DD) ? bf16r(sw[i]) : (unsigned short)0;
}

// ------------- K1: out_s = input @ state_w^T + bias -------------------------
// Wave-private LDS staging, NO barriers (per-wave DS ops are in-order).
// 16 rows/wave, 4 waves/block, 512 blocks (8 waves/CU). K-chunk = 64.
__global__ __launch_bounds__(256) void k_outs(
    const float* __restrict__ inp, const unsigned short* __restrict__ Bw,
    const float* __restrict__ sb, const float* __restrict__ msk,
    float* __restrict__ outs)
{
  __shared__ unsigned short As[4][16 * 72];   // stride 72: 2-way banks (free)
  int tid = threadIdx.x, wave = tid >> 6, lane = tid & 63;
  int quad = lane >> 4, l15 = lane & 15;
  int r0 = blockIdx.x * 64 + wave * 16;
  int srow = lane >> 2, scol = lane & 3;      // staging: 4 lanes per row
  const float* gsrc = inp + (size_t)(r0 + srow) * DD + scol * 4;
  unsigned short* asb = As[wave];
  unsigned* dw = (unsigned*)asb;
  int wbase = srow * 36 + scol * 2;

  f32x4 pre[4];
#pragma unroll
  for (int i = 0; i < 4; ++i) pre[i] = *(const f32x4*)(gsrc + i * 16);

  f32x4 acc[2] = {};
  for (int kc = 0; kc < 12; ++kc) {
#pragma unroll
    for (int i = 0; i < 4; ++i) {
      dw[wbase + i * 8]     = pk2(pre[i][0], pre[i][1]);
      dw[wbase + i * 8 + 1] = pk2(pre[i][2], pre[i][3]);
    }
    if (kc < 11) {
      const float* g2 = gsrc + (kc + 1) * 64;
#pragma unroll
      for (int i = 0; i < 4; ++i) pre[i] = *(const f32x4*)(g2 + i * 16);
    }
#pragma unroll
    for (int ks = 0; ks < 2; ++ks) {
      s16x8 af = *(const s16x8*)(asb + l15 * 72 + ks * 32 + quad * 8);
#pragma unroll
      for (int ct = 0; ct < 2; ++ct) {
        s16x8 bf = *(const s16x8*)(Bw + (ct * 16 + l15) * DD + kc * 64 + ks * 32 + quad * 8);
        acc[ct] = __builtin_amdgcn_mfma_f32_16x16x32_bf16(af, bf, acc[ct], 0, 0, 0);
      }
    }
  }
#pragma unroll
  for (int ct = 0; ct < 2; ++ct) {
    int n = ct * 16 + l15;
    if (n >= NL) continue;
    float b = sb[n];
#pragma unroll
    for (int r = 0; r < 4; ++r) {
      int row = r0 + quad * 4 + r;
      float v = acc[ct][r] + b;
      if (n == IDX_EOS && msk[row] == 0.f) v += 20000.f;
      outs[(size_t)row * NL + n] = v;
    }
  }
}

// ------------- K2 fused: seg blocks (0..1023) + energy blocks (1024..1535) --
__global__ __launch_bounds__(256) void k_main(
    const float* __restrict__ outs, const float* __restrict__ trans,
    const int* __restrict__ target, float* __restrict__ energy,
    unsigned short* __restrict__ Mseg16, float* __restrict__ Sseg,
    float* __restrict__ ws_tgt)
{
  __shared__ float smem[961 + 64 * NL];
  int bid = blockIdx.x;
  int tid = threadIdx.x, wave = tid >> 6, lane = tid & 63;

  if (bid < 1024) {
    // ---- 8-step segment transfer matrices (one wave per unit) ----
    int l = lane & 31, h = lane >> 5;
    int unit = bid * 4 + wave;
    int b = unit >> 6, c = unit & 63;
    int t0 = 1 + c * 8;
    int n = (c == 63) ? 7 : 8;

    float* ub = smem + wave * 256;
#pragma unroll
    for (int it = 0; it < 4; ++it) {
      int idx = lane + it * 64;
      int row = idx >> 5, col = idx & 31;
      float v = 0.f;
      if (col < NL && row < n)
        v = exp2f(LOG2E * outs[((size_t)b * TT + t0 + row) * NL + col]);
      ub[idx] = v;
    }
    __syncthreads();

    Frag8 A1, A2, B1, B2;
#pragma unroll
    for (int m = 0; m < 4; ++m) {
      int k0 = 8 * h + 2 * m, k1 = k0 + 1;
      float a0 = (k0 < NL && l < NL) ? exp2f(LOG2E * trans[k0 * NL + l]) : 0.f;
      float a1 = (k1 < NL && l < NL) ? exp2f(LOG2E * trans[k1 * NL + l]) : 0.f;
      A1.u[m] = pk2(a0, a1);
      int k2 = 16 + k0, k3 = 16 + k1;
      float a2 = (k2 < NL && l < NL) ? exp2f(LOG2E * trans[k2 * NL + l]) : 0.f;
      float a3 = (k3 < NL && l < NL) ? exp2f(LOG2E * trans[k3 * NL + l]) : 0.f;
      A2.u[m] = pk2(a2, a3);
      B1.u[m] = ((k0 == l) ? 0x3f80u : 0u) | (((k1 == l) ? 0x3f80u : 0u) << 16);
      B2.u[m] = ((k2 == l) ? 0x3f80u : 0u) | (((k3 == l) ? 0x3f80u : 0u) << 16);
    }

    float E[16];
    for (int s = 0; s < n; ++s) {
      const float* us = ub + s * 32 + 4 * h;
      f32x4 u0 = *(const f32x4*)(us);
      f32x4 u1 = *(const f32x4*)(us + 8);
      f32x4 u2 = *(const f32x4*)(us + 16);
      f32x4 u3 = *(const f32x4*)(us + 24);
      f32x16 D = {};
      D = __builtin_amdgcn_mfma_f32_32x32x16_bf16(A1.s, B1.s, D, 0, 0, 0);
      D = __builtin_amdgcn_mfma_f32_32x32x16_bf16(A2.s, B2.s, D, 0, 0, 0);
#pragma unroll
      for (int jj = 0; jj < 4; ++jj) {
        E[jj]      = D[jj]      * u0[jj];
        E[4 + jj]  = D[4 + jj]  * u1[jj];
        E[8 + jj]  = D[8 + jj]  * u2[jj];
        E[12 + jj] = D[12 + jj] * u3[jj];
      }
      if (s + 1 < n) repack(E, h, B1, B2);
    }
    float S = 0.f;
    renorm16(E, S);
    unsigned short* mo = Mseg16 + (size_t)unit * 1024;
#pragma unroll
    for (int r = 0; r < 16; ++r) {
      int row = (r & 3) + 8 * (r >> 2) + 4 * h;
      mo[row * 32 + l] = bf16r(E[r]);
    }
    if (lane == 0) Sseg[unit] = S;
    return;
  }

  // ---- energy blocks: 64 rows, vectorized flat dwordx4 stores ----
  int r0 = (bid - 1024) * 64;
  float* tr  = smem;            // 961
  float* osh = smem + 961;      // 64*31
  for (int idx = tid; idx < 961; idx += 256) tr[idx] = trans[idx];
  for (int idx = tid; idx < 64 * NL; idx += 256)
    osh[idx] = outs[(size_t)r0 * NL + idx];
  __syncthreads();

  if (tid < 64) {
    int r = r0 + tid;
    int tg = target[r];
    int prv = ((r & (TT - 1)) == 0) ? IDX_BOS : target[r - 1];
    float cc = tr[prv * NL + tg] + osh[tid * NL + tg];
#pragma unroll
    for (int off = 32; off; off >>= 1) cc += __shfl_down(cc, off);
    if (tid == 0) atomicAdd(&ws_tgt[r0 / TT], cc);
  }

  // flat region: 64*961 = 61504 f32 = 15376 vec4 (base 16B-aligned)
  float* dst = energy + (size_t)r0 * 961;
#pragma unroll 4
  for (int it = 0; it < 60; ++it) {
    int v = it * 256 + tid;
    int e = v * 4;
    f32x4 val;
#pragma unroll
    for (int k = 0; k < 4; ++k) {
      unsigned x = e + k;
      unsigned q = __umulhi(x, 4469269u);        // x / 961 (exact, x < 20M)
      unsigned c = x - q * 961u;
      unsigned j = c - 31u * ((c * 67651u) >> 21); // c % 31 (exact, c < 961)
      val[k] = tr[c] + osh[q * NL + j];
    }
    *(f32x4*)(dst + e) = val;
  }
  if (tid < 16) {
    int e = (15360 + tid) * 4;
    f32x4 val;
#pragma unroll
    for (int k = 0; k < 4; ++k) {
      unsigned x = e + k;
      unsigned q = __umulhi(x, 4469269u);
      unsigned c = x - q * 961u;
      unsigned j = c - 31u * ((c * 67651u) >> 21);
      val[k] = tr[c] + osh[q * NL + j];
    }
    *(f32x4*)(dst + e) = val;
  }
}

// ------------- K3: quad products Q = M3*M2*M1*M0 (bf16 in/out) --------------
__global__ __launch_bounds__(256) void k_tree1(
    const unsigned short* __restrict__ Mseg16, const float* __restrict__ Sseg,
    unsigned short* __restrict__ Mq16, float* __restrict__ Sq)
{
  int tid = threadIdx.x, wave = tid >> 6, lane = tid & 63;
  int l = lane & 31, h = lane >> 5;
  int unit = blockIdx.x * 4 + wave;
  const unsigned short* base = Mseg16 + (size_t)unit * 4096;
  Frag8 A1, A2, B1, B2;
  load_B16(base, l, h, B1, B2);
  float S = Sseg[unit * 4] + Sseg[unit * 4 + 1] + Sseg[unit * 4 + 2] + Sseg[unit * 4 + 3];
  float E[16];
#pragma unroll
  for (int i = 1; i < 4; ++i) {
    load_A16(base + i * 1024, l, h, A1, A2);
    f32x16 D = {};
    D = __builtin_amdgcn_mfma_f32_32x32x16_bf16(A1.s, B1.s, D, 0, 0, 0);
    D = __builtin_amdgcn_mfma_f32_32x32x16_bf16(A2.s, B2.s, D, 0, 0, 0);
#pragma unroll
    for (int r = 0; r < 16; ++r) E[r] = D[r];
    if (i < 3) repack(E, h, B1, B2);
  }
  renorm16(E, S);
  unsigned short* mo = Mq16 + (size_t)unit * 1024;
#pragma unroll
  for (int r = 0; r < 16; ++r) {
    int row = (r & 3) + 8 * (r >> 2) + 4 * h;
    mo[row * 32 + l] = bf16r(E[r]);
  }
  if (lane == 0) Sq[unit] = S;
}

// ------------- K4: per-batch final product + lse + loss ---------------------
__global__ __launch_bounds__(256) void k_tree2(
    const float* __restrict__ outs, const float* __restrict__ trans,
    const unsigned short* __restrict__ Mq16, const float* __restrict__ Sq,
    const float* __restrict__ ws_tgt, float* __restrict__ loss)
{
  int tid = threadIdx.x, wave = tid >> 6, lane = tid & 63;
  int l = lane & 31, h = lane >> 5;
  int b = blockIdx.x * 4 + wave;
  const unsigned short* base = Mq16 + (size_t)b * 16384;
  Frag8 A1, A2, B1, B2;
  load_B16(base, l, h, B1, B2);
  float S = 0.f;
#pragma unroll
  for (int q = 0; q < 16; ++q) S += Sq[b * 16 + q];
  float E[16];
  for (int i = 1; i < 16; ++i) {
    load_A16(base + i * 1024, l, h, A1, A2);
    f32x16 D = {};
    D = __builtin_amdgcn_mfma_f32_32x32x16_bf16(A1.s, B1.s, D, 0, 0, 0);
    D = __builtin_amdgcn_mfma_f32_32x32x16_bf16(A2.s, B2.s, D, 0, 0, 0);
#pragma unroll
    for (int r = 0; r < 16; ++r) E[r] = D[r];
    if ((i & 3) == 3) renorm16(E, S);
    if (i < 15) repack(E, h, B1, B2);
  }
  float p0 = (l < NL) ? exp2f(LOG2E * (trans[IDX_BOS * NL + l] + outs[(size_t)b * TT * NL + l])) : 0.f;
  float sum_h = 0.f;
#pragma unroll
  for (int r = 0; r < 16; ++r) {
    float s = bfly_sum32(E[r] * p0);
    int row = (r & 3) + 8 * (r >> 2) + 4 * h;
    float We = (row < NL) ? exp2f(LOG2E * trans[row * NL + IDX_EOS]) : 0.f;
    sum_h += s * We;
  }
  float tot = sum_h + __shfl_xor(sum_h, 32);
  if (lane == 0) loss[b] = LN2F * (S + log2f(tot)) - ws_tgt[b];
}

extern "C" void kernel_launch(void* const* d_in, const int* in_sizes, int n_in,
                              void* d_out, int out_size, void* d_ws, size_t ws_size,
                              hipStream_t stream) {
  const float* inp   = (const float*)d_in[0];   // (64,512,768) f32
  const int*   tgt   = (const int*)d_in[1];     // (64,512) int
  const float* msk   = (const float*)d_in[2];   // (64,512) f32
  const float* sw    = (const float*)d_in[3];   // (31,768) f32
  const float* sb    = (const float*)d_in[4];   // (31,) f32
  const float* trans = (const float*)d_in[5];   // (31,31) f32

  float* out    = (float*)d_out;
  float* loss   = out;
  float* energy = out + BB;

  // d_ws layout (~14.6 MB; ws is ~378 MB per poison-fill evidence):
  float* outs   = (float*)d_ws;                       // 32768*31 f32
  float* Sseg   = outs + (size_t)RTOT * NL;           // 4096
  float* Sq     = Sseg + 4096;                        // 1024
  float* ws_tgt = Sq + 1024;                          // 64
  unsigned short* Mseg16 = (unsigned short*)(ws_tgt + 64);   // 4096*1024 bf16
  unsigned short* Mq16   = Mseg16 + (size_t)4096 * 1024;     // 1024*1024 bf16
  unsigned short* Bw     = Mq16 + (size_t)1024 * 1024;       // 32*768 bf16

  k_prep<<<8, 256, 0, stream>>>(sw, Bw, ws_tgt);
  k_outs<<<RTOT / 64, 256, 0, stream>>>(inp, Bw, sb, msk, outs);
  k_main<<<1536, 256, 0, stream>>>(outs, trans, tgt, energy, Mseg16, Sseg, ws_tgt);
  k_tree1<<<256, 256, 0, stream>>>(Mseg16, Sseg, Mq16, Sq);
  k_tree2<<<16, 256, 0, stream>>>(outs, trans, Mq16, Sq, ws_tgt, loss);
}